// Round 8
// baseline (24.894 us; speedup 1.0000x reference)
//
#include <hip/hip_runtime.h>
#include <hip/hip_bf16.h>
#include <math.h>

#define NS 512
#define OD 128
#define BB 64
#define TT 2000
#define KK 400
#define CHUNK 128
#define NCH 16
#define NAUX (NS + 1 + BB)
#define LOG2PI_F 1.8378770664093453f
#define SEQ_OFF  576      // ws float offset: per-batch seq partials [BB]
#define PART_OFF 1024     // ws float offset: obs partials [BB*NCH]

// ws layout (floats):
//   [0,512) row_lse   [512] init_lse
//   [SEQ_OFF,+64)   duration + trans-numerator + init_logit partial per batch
//   [PART_OFF,+1024) obs partials (scaled by -0.5)

__device__ __forceinline__ float softplusf(float x) {
    return (x > 20.f) ? x : log1pf(expf(x));
}

// grid: [0,NS+1) lse | [NS+1,NAUX) seq | [NAUX, NAUX+BB*NCH) obs
// aux blocks first so they don't extend the dispatch tail.
__global__ __launch_bounds__(256) void big_kernel(
    const float* __restrict__ obs, const float* __restrict__ mu,
    const float* __restrict__ lvar, const float* __restrict__ trans,
    const float* __restrict__ init_logits,
    const float* __restrict__ alpha_p, const float* __restrict__ beta_p,
    const int* __restrict__ states, const int* __restrict__ durs,
    float* __restrict__ ws)
{
    const int tid = threadIdx.x;
    const int bid = blockIdx.x;
    __shared__ float red[4];

    if (bid < NS + 1) {
        // ---- LSE: transition row r<512, or initial logits (r==512) ----
        const int r = bid;
        const float* src = (r < NS) ? (trans + (size_t)r * NS) : init_logits;
        float x0 = src[tid];
        float x1 = src[tid + 256];
        float m = fmaxf(x0, x1);
        for (int off = 32; off; off >>= 1) m = fmaxf(m, __shfl_down(m, off, 64));
        if ((tid & 63) == 0) red[tid >> 6] = m;
        __syncthreads();
        m = fmaxf(fmaxf(red[0], red[1]), fmaxf(red[2], red[3]));
        __syncthreads();
        float e = __expf(x0 - m) + __expf(x1 - m);
        for (int off = 32; off; off >>= 1) e += __shfl_down(e, off, 64);
        if ((tid & 63) == 0) red[tid >> 6] = e;
        __syncthreads();
        if (tid == 0)
            ws[(r < NS) ? r : 512] = m + __logf(red[0] + red[1] + red[2] + red[3]);
    } else if (bid < NAUX) {
        // ---- seq: duration terms + transition numerators + init logit ----
        const int b = bid - (NS + 1);
        float lp = 0.f;
        for (int k = tid; k < KK; k += 256) {
            const int s = states[b * KK + k];
            const float dv = (float)durs[b * KK + k];
            const float a  = softplusf(alpha_p[s]) + 1e-6f;
            const float bt = softplusf(beta_p[s]) + 1e-6f;
            float v = (a - 1.f) * __logf(dv + 1e-8f) - bt * dv
                    + a * __logf(bt) - lgammaf(a);
            lp += (dv >= 1.f) ? v : -INFINITY;
            if (k < KK - 1)
                lp += trans[(size_t)s * NS + states[b * KK + k + 1]];
        }
        for (int off = 32; off; off >>= 1) lp += __shfl_down(lp, off, 64);
        if ((tid & 63) == 0) red[tid >> 6] = lp;
        __syncthreads();
        if (tid == 0)
            ws[SEQ_OFF + b] = red[0] + red[1] + red[2] + red[3]
                            + init_logits[states[b * KK]];
    } else {
        // ---- observation partial for (batch b, 128-frame chunk) ----
        const int ob = bid - NAUX;
        const int b = ob >> 4;
        const int t0 = (ob & 15) * CHUNK;

        __shared__ int fsl[CHUNK];
        __shared__ int csum[8];

        // states+durations -> registers; wave-shuffle inclusive scan of durs
        const int lane = tid & 63, w = tid >> 6;
        int s0v = states[b * KK + tid];            // tid < 400 always
        int d0  = durs[b * KK + tid];
        int s1v = 0, d1 = 0;
        if (tid + 256 < KK) {
            s1v = states[b * KK + tid + 256];
            d1  = durs[b * KK + tid + 256];
        }
        int v0 = d0, v1 = d1;
        #pragma unroll
        for (int off = 1; off < 64; off <<= 1) {
            int u0 = __shfl_up(v0, off, 64);
            int u1 = __shfl_up(v1, off, 64);
            if (lane >= off) { v0 += u0; v1 += u1; }
        }
        if (lane == 63) { csum[w] = v0; csum[4 + w] = v1; }
        __syncthreads();
        int off0 = 0, off1 = 0;
        #pragma unroll
        for (int c = 0; c < 8; ++c) {
            int cs = csum[c];
            off0 += (c < w) ? cs : 0;
            off1 += (c < 4 + w) ? cs : 0;
        }
        const int c0 = v0 + off0;      // cum[tid]
        const int c1 = v1 + off1;      // cum[tid+256]

        // interval-expand: thread k writes its segment's frames in this chunk.
        {
            int a = c0 - d0, e = c0;
            a = (a < t0) ? t0 : a;
            e = (e > t0 + CHUNK) ? t0 + CHUNK : e;
            for (int t = a; t < e; ++t) fsl[t - t0] = s0v;
            int a1 = c1 - d1, e1 = (tid + 256 == KK - 1) ? t0 + CHUNK : c1;
            a1 = (a1 < t0) ? t0 : a1;
            e1 = (e1 > t0 + CHUNK) ? t0 + CHUNK : e1;
            for (int t = a1; t < e1; ++t) fsl[t - t0] = s1v;
        }
        __syncthreads();

        // one wave per frame: s is wave-uniform; mu/exp(-lv) cached in regs
        // across the segment run; 1 float2 obs load per frame, pipelined 1 deep.
        const int base = w * 32;                       // this wave's frame span
        const int tstart = t0 + base;
        int nf = TT - tstart;
        nf = (nf > 32) ? 32 : nf;
        float acc = 0.f;
        if (nf > 0) {
            const float* obase = obs + ((size_t)b * TT + tstart) * OD + lane * 2;
            int s_prev = -1;
            float2 m2, w2;
            float cl = 0.f;
            int s_next = fsl[base];
            float2 o_next = *(const float2*)(obase);
            for (int i = 0; i < nf; ++i) {
                const int s_cur = s_next;
                const float2 o = o_next;
                if (i + 1 < nf) {
                    s_next = fsl[base + i + 1];
                    o_next = *(const float2*)(obase + (size_t)(i + 1) * OD);
                }
                if (s_cur != s_prev) {                  // wave-uniform branch
                    s_prev = s_cur;
                    m2 = *(const float2*)(mu + (size_t)s_cur * OD + lane * 2);
                    const float2 lv = *(const float2*)(lvar + (size_t)s_cur * OD + lane * 2);
                    w2.x = __expf(-lv.x);
                    w2.y = __expf(-lv.y);
                    cl = lv.x + lv.y + 2.f * LOG2PI_F;
                }
                const float dx = o.x - m2.x, dy = o.y - m2.y;
                acc += cl + dx * dx * w2.x + dy * dy * w2.y;
            }
        }
        for (int off = 32; off; off >>= 1) acc += __shfl_down(acc, off, 64);
        if ((tid & 63) == 0) red[tid >> 6] = acc;
        __syncthreads();
        if (tid == 0)
            ws[PART_OFF + ob] = -0.5f * (red[0] + red[1] + red[2] + red[3]);
    }
}

__global__ __launch_bounds__(256) void fin_kernel(
    const int* __restrict__ states, const float* __restrict__ ws,
    float* __restrict__ out)
{
    const int b = blockIdx.x;
    const int tid = threadIdx.x;
    __shared__ float red[4];

    float lp = 0.f;
    if (tid < NCH)       lp = ws[PART_OFF + b * NCH + tid];
    else if (tid == NCH) lp = ws[SEQ_OFF + b] - ws[512];
    // subtract row_lse for each transition (2 KB table, L1-hot)
    for (int k = tid; k < KK - 1; k += 256)
        lp -= ws[states[b * KK + k]];
    for (int off = 32; off; off >>= 1) lp += __shfl_down(lp, off, 64);
    if ((tid & 63) == 0) red[tid >> 6] = lp;
    __syncthreads();
    if (tid == 0)
        out[b] = red[0] + red[1] + red[2] + red[3];
}

extern "C" void kernel_launch(void* const* d_in, const int* in_sizes, int n_in,
                              void* d_out, int out_size, void* d_ws, size_t ws_size,
                              hipStream_t stream) {
    const float* observations = (const float*)d_in[0];
    const float* alpha_p      = (const float*)d_in[1];
    const float* beta_p       = (const float*)d_in[2];
    const float* trans        = (const float*)d_in[3];
    const float* init_logits  = (const float*)d_in[4];
    const float* obs_means    = (const float*)d_in[5];
    const float* obs_logvars  = (const float*)d_in[6];
    const int*   state_seq    = (const int*)d_in[7];
    const int*   dur_seq      = (const int*)d_in[8];

    float* ws = (float*)d_ws;
    float* out = (float*)d_out;

    big_kernel<<<NAUX + BB * NCH, 256, 0, stream>>>(
        observations, obs_means, obs_logvars, trans, init_logits,
        alpha_p, beta_p, state_seq, dur_seq, ws);
    fin_kernel<<<BB, 256, 0, stream>>>(state_seq, ws, out);
}

// Round 9
// 23.786 us; speedup vs baseline: 1.0466x; 1.0466x over previous
//
#include <hip/hip_runtime.h>
#include <hip/hip_bf16.h>
#include <math.h>

#define NS 512
#define OD 128
#define BB 64
#define TT 2000
#define KK 400
#define CHUNK 128
#define NCH 16
#define LOG2PI_F 1.8378770664093453f
#define SEQ_OFF  576      // ws float offset: per-batch seq partials [BB]
#define PART_OFF 1024     // ws float offset: obs partials [BB*NCH]

// ws layout (floats):
//   [0,512) row_lse   [512] init_lse
//   [SEQ_OFF,+64)   duration + trans-numerator + init_logit partial per batch
//   [PART_OFF,+1024) obs partials (scaled by -0.5)

__device__ __forceinline__ float softplusf(float x) {
    return (x > 20.f) ? x : log1pf(expf(x));
}

// grid: [0, BB*NCH) obs | [BB*NCH, +NS+1) lse | [+BB) seq. No cross-block deps.
__global__ __launch_bounds__(256) void big_kernel(
    const float* __restrict__ obs, const float* __restrict__ mu,
    const float* __restrict__ lvar, const float* __restrict__ trans,
    const float* __restrict__ init_logits,
    const float* __restrict__ alpha_p, const float* __restrict__ beta_p,
    const int* __restrict__ states, const int* __restrict__ durs,
    float* __restrict__ ws)
{
    const int tid = threadIdx.x;
    const int bid = blockIdx.x;
    __shared__ float red[4];

    if (bid < BB * NCH) {
        // ---- observation partial for (batch b, 128-frame chunk) ----
        const int b = bid >> 4;
        const int t0 = (bid & 15) * CHUNK;

        __shared__ int fsl[CHUNK];
        __shared__ int csum[8];

        // states+durations -> registers; wave-shuffle inclusive scan of durs
        const int lane = tid & 63, w = tid >> 6;
        int s0v = states[b * KK + tid];            // tid < 400 always
        int d0  = durs[b * KK + tid];
        int s1v = 0, d1 = 0;
        if (tid + 256 < KK) {
            s1v = states[b * KK + tid + 256];
            d1  = durs[b * KK + tid + 256];
        }
        int v0 = d0, v1 = d1;
        #pragma unroll
        for (int off = 1; off < 64; off <<= 1) {
            int u0 = __shfl_up(v0, off, 64);
            int u1 = __shfl_up(v1, off, 64);
            if (lane >= off) { v0 += u0; v1 += u1; }
        }
        if (lane == 63) { csum[w] = v0; csum[4 + w] = v1; }
        __syncthreads();
        int off0 = 0, off1 = 0;
        #pragma unroll
        for (int c = 0; c < 8; ++c) {
            int cs = csum[c];
            off0 += (c < w) ? cs : 0;
            off1 += (c < 4 + w) ? cs : 0;
        }
        const int c0 = v0 + off0;      // cum[tid]
        const int c1 = v1 + off1;      // cum[tid+256]

        // interval-expand: thread k writes its segment's frames in this chunk.
        {
            int a = c0 - d0, e = c0;
            a = (a < t0) ? t0 : a;
            e = (e > t0 + CHUNK) ? t0 + CHUNK : e;
            for (int t = a; t < e; ++t) fsl[t - t0] = s0v;
            int a1 = c1 - d1, e1 = (tid + 256 == KK - 1) ? t0 + CHUNK : c1;
            a1 = (a1 < t0) ? t0 : a1;
            e1 = (e1 > t0 + CHUNK) ? t0 + CHUNK : e1;
            for (int t = a1; t < e1; ++t) fsl[t - t0] = s1v;
        }
        __syncthreads();

        const int row = tid >> 5;          // 8 frames per iter
        const int dd = (tid & 31) * 4;
        const float* obase = obs + ((size_t)b * TT + t0) * OD + dd;
        float acc = 0.f;
        if (t0 + CHUNK <= TT) {
            // 2 groups of 8 fully-unrolled frame-iters: batch all 8 obs row
            // loads into registers FIRST (8 KB/wave in flight), then consume.
            #pragma unroll
            for (int g = 0; g < 2; ++g) {
                float4 ov[8];
                #pragma unroll
                for (int j = 0; j < 8; ++j)
                    ov[j] = *(const float4*)(obase
                              + (size_t)((g * 8 + j) * 8 + row) * OD);
                #pragma unroll
                for (int j = 0; j < 8; ++j) {
                    const int s = fsl[(g * 8 + j) * 8 + row];
                    const float4 m  = *(const float4*)(mu  + (size_t)s * OD + dd);
                    const float4 lv = *(const float4*)(lvar + (size_t)s * OD + dd);
                    const float dx = ov[j].x - m.x, dy = ov[j].y - m.y,
                                dz = ov[j].z - m.z, dw = ov[j].w - m.w;
                    acc += lv.x + lv.y + lv.z + lv.w + 4.f * LOG2PI_F
                         + dx * dx * __expf(-lv.x) + dy * dy * __expf(-lv.y)
                         + dz * dz * __expf(-lv.z) + dw * dw * __expf(-lv.w);
                }
            }
        } else {
            #pragma unroll
            for (int i = 0; i < CHUNK / 8; ++i) {
                const int t = t0 + i * 8 + row;
                if (t < TT) {
                    const int s = fsl[i * 8 + row];
                    const float4 o  = *(const float4*)(obs + ((size_t)(b * TT + t)) * OD + dd);
                    const float4 m  = *(const float4*)(mu  + (size_t)s * OD + dd);
                    const float4 lv = *(const float4*)(lvar + (size_t)s * OD + dd);
                    const float dx = o.x - m.x, dy = o.y - m.y, dz = o.z - m.z, dw = o.w - m.w;
                    acc += lv.x + lv.y + lv.z + lv.w + 4.f * LOG2PI_F
                         + dx * dx * __expf(-lv.x) + dy * dy * __expf(-lv.y)
                         + dz * dz * __expf(-lv.z) + dw * dw * __expf(-lv.w);
                }
            }
        }
        for (int off = 32; off; off >>= 1) acc += __shfl_down(acc, off, 64);
        if ((tid & 63) == 0) red[tid >> 6] = acc;
        __syncthreads();
        if (tid == 0)
            ws[PART_OFF + bid] = -0.5f * (red[0] + red[1] + red[2] + red[3]);
    } else if (bid < BB * NCH + NS + 1) {
        // ---- LSE: transition row r<512, or initial logits (r==512) ----
        const int r = bid - BB * NCH;
        const float* src = (r < NS) ? (trans + (size_t)r * NS) : init_logits;
        float x0 = src[tid];
        float x1 = src[tid + 256];
        float m = fmaxf(x0, x1);
        for (int off = 32; off; off >>= 1) m = fmaxf(m, __shfl_down(m, off, 64));
        if ((tid & 63) == 0) red[tid >> 6] = m;
        __syncthreads();
        m = fmaxf(fmaxf(red[0], red[1]), fmaxf(red[2], red[3]));
        __syncthreads();
        float e = __expf(x0 - m) + __expf(x1 - m);
        for (int off = 32; off; off >>= 1) e += __shfl_down(e, off, 64);
        if ((tid & 63) == 0) red[tid >> 6] = e;
        __syncthreads();
        if (tid == 0)
            ws[(r < NS) ? r : 512] = m + __logf(red[0] + red[1] + red[2] + red[3]);
    } else {
        // ---- seq: duration terms + transition numerators + init logit ----
        const int b = bid - (BB * NCH + NS + 1);
        float lp = 0.f;
        for (int k = tid; k < KK; k += 256) {
            const int s = states[b * KK + k];
            const float dv = (float)durs[b * KK + k];
            const float a  = softplusf(alpha_p[s]) + 1e-6f;
            const float bt = softplusf(beta_p[s]) + 1e-6f;
            float v = (a - 1.f) * __logf(dv + 1e-8f) - bt * dv
                    + a * __logf(bt) - lgammaf(a);
            lp += (dv >= 1.f) ? v : -INFINITY;
            if (k < KK - 1)
                lp += trans[(size_t)s * NS + states[b * KK + k + 1]];
        }
        for (int off = 32; off; off >>= 1) lp += __shfl_down(lp, off, 64);
        if ((tid & 63) == 0) red[tid >> 6] = lp;
        __syncthreads();
        if (tid == 0)
            ws[SEQ_OFF + b] = red[0] + red[1] + red[2] + red[3]
                            + init_logits[states[b * KK]];
    }
}

__global__ __launch_bounds__(256) void fin_kernel(
    const int* __restrict__ states, const float* __restrict__ ws,
    float* __restrict__ out)
{
    const int b = blockIdx.x;
    const int tid = threadIdx.x;
    __shared__ float red[4];

    float lp = 0.f;
    if (tid < NCH)       lp = ws[PART_OFF + b * NCH + tid];
    else if (tid == NCH) lp = ws[SEQ_OFF + b] - ws[512];
    // subtract row_lse for each transition (2 KB table, L1-hot)
    for (int k = tid; k < KK - 1; k += 256)
        lp -= ws[states[b * KK + k]];
    for (int off = 32; off; off >>= 1) lp += __shfl_down(lp, off, 64);
    if ((tid & 63) == 0) red[tid >> 6] = lp;
    __syncthreads();
    if (tid == 0)
        out[b] = red[0] + red[1] + red[2] + red[3];
}

extern "C" void kernel_launch(void* const* d_in, const int* in_sizes, int n_in,
                              void* d_out, int out_size, void* d_ws, size_t ws_size,
                              hipStream_t stream) {
    const float* observations = (const float*)d_in[0];
    const float* alpha_p      = (const float*)d_in[1];
    const float* beta_p       = (const float*)d_in[2];
    const float* trans        = (const float*)d_in[3];
    const float* init_logits  = (const float*)d_in[4];
    const float* obs_means    = (const float*)d_in[5];
    const float* obs_logvars  = (const float*)d_in[6];
    const int*   state_seq    = (const int*)d_in[7];
    const int*   dur_seq      = (const int*)d_in[8];

    float* ws = (float*)d_ws;
    float* out = (float*)d_out;

    big_kernel<<<BB * NCH + NS + 1 + BB, 256, 0, stream>>>(
        observations, obs_means, obs_logvars, trans, init_logits,
        alpha_p, beta_p, state_seq, dur_seq, ws);
    fin_kernel<<<BB, 256, 0, stream>>>(state_seq, ws, out);
}